// Round 4
// baseline (2450.275 us; speedup 1.0000x reference)
//
#include <hip/hip_runtime.h>
#include <hip/hip_bf16.h>

#define T_STEPS 512
#define HID 512
#define EMB_D 300
#define BATCH 64
#define NCLS 1000

typedef __attribute__((ext_vector_type(4))) float f32x4;
typedef __attribute__((ext_vector_type(8))) short bf16x8;
typedef __attribute__((ext_vector_type(4))) unsigned int u32x4;
typedef __attribute__((ext_vector_type(2))) unsigned int u32x2;

union FragU { u32x4 u; bf16x8 b; };

__device__ __forceinline__ unsigned cvtpk(float lo, float hi) {
  unsigned r;
  asm("v_cvt_pk_bf16_f32 %0, %1, %2" : "=v"(r) : "v"(lo), "v"(hi));
  return r;
}

__device__ __forceinline__ bf16x8 pack8(f32x4 lo, f32x4 hi) {
  FragU u;
  u.u = (u32x4){cvtpk(lo.x, lo.y), cvtpk(lo.z, lo.w), cvtpk(hi.x, hi.y), cvtpk(hi.z, hi.w)};
  return u.b;
}

__device__ __forceinline__ float tanh_fast(float x) {
  x = fminf(15.0f, fmaxf(-15.0f, x));
  float e = __builtin_amdgcn_exp2f(x * 2.8853900817779268f);
  return (e - 1.0f) * __builtin_amdgcn_rcpf(e + 1.0f);
}

#define MFMA16(A, B, C) __builtin_amdgcn_mfma_f32_16x16x32_bf16(A, B, C, 0, 0, 0)

// ---------------------------------------------------------------------------
// K0: pack W_hh (f32) -> bf16 MFMA B-fragments in ws.
// wpack[wv 8][tile 4][kk 16][lane 64][e 8]: value = Whh[wv*64+tile*16+c][kk*32+g*8+e]
// (c = lane&15, g = lane>>4). 512 KB; L2-resident per XCD during K2.
// ---------------------------------------------------------------------------
__global__ __launch_bounds__(256) void k0_pack(const float* __restrict__ Whh,
                                               unsigned short* __restrict__ wpack) {
  const int idx = blockIdx.x * 256 + threadIdx.x;  // 0..32767 lane-frags
  const int lane = idx & 63;
  const int kk = (idx >> 6) & 15;
  const int tw = (idx >> 10) & 3;
  const int wv = idx >> 12;
  const int c = lane & 15, g = lane >> 4;
  const int i = wv * 64 + tw * 16 + c;
  const int j = kk * 32 + g * 8;
  f32x4 lo = *(const f32x4*)(Whh + (size_t)i * HID + j);
  f32x4 hi = *(const f32x4*)(Whh + (size_t)i * HID + j + 4);
  *(bf16x8*)(wpack + (size_t)idx * 8) = pack8(lo, hi);
}

// ---------------------------------------------------------------------------
// K1 v2: xp[t][n][b] = emb[x[b,t]] . W_ih[n,:] + b_ih[n] + b_hh[n]
// One block per t: stage 64 emb rows to LDS as bf16 ONCE (kills the 32x
// re-gather of round-0), hold all 40 A-frags in regs, loop 8 n-tiles/wave.
// ---------------------------------------------------------------------------
__global__ __launch_bounds__(256) void k1_embed_proj(
    const int* __restrict__ x, const float* __restrict__ emb,
    const float* __restrict__ Wih, const float* __restrict__ bih,
    const float* __restrict__ bhh, unsigned short* __restrict__ xp) {
  __shared__ unsigned short xe[64][328];   // stride 328 shorts: 16B-aligned rows, 2-way banks
  __shared__ int xi[64];
  const int tid = threadIdx.x;
  const int t = blockIdx.x;
  if (tid < 64) xi[tid] = x[tid * T_STEPS + t];
  __syncthreads();
  {
    const int r = tid >> 2, q = tid & 3;
    const float* src = emb + (size_t)xi[r] * EMB_D;
    for (int jp = q; jp < 150; jp += 4) {
      const int j = jp * 2;
      *(unsigned*)&xe[r][j] = cvtpk(src[j], src[j + 1]);
    }
    if (q == 3) {
      #pragma unroll
      for (int j = 300; j < 328; j += 2) *(unsigned*)&xe[r][j] = 0;  // zero K-pad
    }
  }
  __syncthreads();

  const int wv = tid >> 6, lane = tid & 63;
  const int c = lane & 15, g = lane >> 4;
  const f32x4 z4 = {0, 0, 0, 0};

  bf16x8 af[4][10];                         // 40 frags = 160 VGPRs, static idx
  #pragma unroll
  for (int a = 0; a < 4; ++a) {
    #pragma unroll
    for (int kk = 0; kk < 10; ++kk)
      af[a][kk] = *(const bf16x8*)&xe[a * 16 + c][kk * 32 + g * 8];
  }

  #pragma unroll 1
  for (int nt8 = 0; nt8 < 8; ++nt8) {
    const int n = (wv * 8 + nt8) * 16 + c;
    f32x4 a0 = z4, a1 = z4, a2 = z4, a3 = z4;
    #pragma unroll
    for (int kk = 0; kk < 10; ++kk) {
      const int k0 = kk * 32 + g * 8;
      f32x4 blo = (k0 < EMB_D) ? *(const f32x4*)(Wih + (size_t)n * EMB_D + k0) : z4;
      f32x4 bhi = (k0 + 4 < EMB_D) ? *(const f32x4*)(Wih + (size_t)n * EMB_D + k0 + 4) : z4;
      bf16x8 bfrag = pack8(blo, bhi);
      a0 = MFMA16(af[0][kk], bfrag, a0);
      a1 = MFMA16(af[1][kk], bfrag, a1);
      a2 = MFMA16(af[2][kk], bfrag, a2);
      a3 = MFMA16(af[3][kk], bfrag, a3);
    }
    const float bias = bih[n] + bhh[n];
    #pragma unroll
    for (int a = 0; a < 4; ++a) {
      f32x4 o = ((a == 0) ? a0 : (a == 1) ? a1 : (a == 2) ? a2 : a3) + bias;
      u32x2 pk = {cvtpk(o.x, o.y), cvtpk(o.z, o.w)};
      *(u32x2*)(xp + ((size_t)t * HID + n) * BATCH + a * 16 + g * 4) = pk;
    }
  }
}

// ---------------------------------------------------------------------------
// K2 v2: persistent RNN, 4 WGs x 512 thr. Wave owns 64 cols; W_hh tiles 0,1
// register-resident (128 VGPR), tiles 2,3 STREAMED from L2-resident wpack each
// step (grouped 4-kk prefetch, 1 group ahead). LDS = h double-buffer only.
// ---------------------------------------------------------------------------
__global__ __launch_bounds__(512) void k2_rnn(
    const unsigned short* __restrict__ wpack,
    const unsigned short* __restrict__ xp, float* __restrict__ hT) {
  __shared__ unsigned short hbuf[2][16][520];   // 33,280 B total LDS
  const int tid = threadIdx.x;
  const int wv = tid >> 6, lane = tid & 63;
  const int c = lane & 15, g = lane >> 4;
  const int wg = blockIdx.x;                    // batch rows wg*16..+15
  const int n_wave = wv * 64;

  const unsigned short* wp = wpack + (size_t)wv * 64 * 512 + (size_t)lane * 8;
  bf16x8 wr0[16], wr1[16];
  #pragma unroll
  for (int kk = 0; kk < 16; ++kk) {
    wr0[kk] = *(const bf16x8*)(wp + (size_t)kk * 512);
    wr1[kk] = *(const bf16x8*)(wp + (size_t)(16 + kk) * 512);
  }
  const unsigned short* wp2 = wp + 32 * 512;
  const unsigned short* wp3 = wp + 48 * 512;

  for (int i = tid; i < 2 * 16 * 520; i += 512) ((unsigned short*)hbuf)[i] = 0;
  __syncthreads();

  const unsigned short* xpp = xp + (size_t)(n_wave + c) * BATCH + wg * 16 + g * 4;
  int cur = 0;

  #pragma unroll 1
  for (int t = 0; t < T_STEPS; ++t) {
    u32x2 xq0 = *(const u32x2*)(xpp);
    u32x2 xq1 = *(const u32x2*)(xpp + 1024);
    u32x2 xq2 = *(const u32x2*)(xpp + 2048);
    u32x2 xq3 = *(const u32x2*)(xpp + 3072);

    f32x4 acc0 = {0,0,0,0}, acc1 = {0,0,0,0}, acc2 = {0,0,0,0}, acc3 = {0,0,0,0};
    const unsigned short* hb = &hbuf[cur][0][0];

    bf16x8 w2b[16], w3b[16];                   // streamed; liveness = ~2 groups
    #pragma unroll
    for (int q = 0; q < 4; ++q) {
      w2b[q] = *(const bf16x8*)(wp2 + (size_t)q * 512);
      w3b[q] = *(const bf16x8*)(wp3 + (size_t)q * 512);
    }
    #pragma unroll
    for (int G = 0; G < 4; ++G) {
      if (G < 3) {                              // prefetch next 4-kk group
        const unsigned short* p2 = wp2 + (size_t)(G + 1) * 4 * 512;
        const unsigned short* p3 = wp3 + (size_t)(G + 1) * 4 * 512;
        #pragma unroll
        for (int q = 0; q < 4; ++q) {
          w2b[G * 4 + 4 + q] = *(const bf16x8*)(p2 + (size_t)q * 512);
          w3b[G * 4 + 4 + q] = *(const bf16x8*)(p3 + (size_t)q * 512);
        }
      }
      #pragma unroll
      for (int q = 0; q < 4; ++q) {
        const int kk = G * 4 + q;
        bf16x8 afr = *(const bf16x8*)(hb + c * 520 + kk * 32 + g * 8);
        acc0 = MFMA16(afr, wr0[kk], acc0);
        acc1 = MFMA16(afr, wr1[kk], acc1);
        acc2 = MFMA16(afr, w2b[kk], acc2);
        acc3 = MFMA16(afr, w3b[kk], acc3);
      }
    }

    unsigned short* hw = &hbuf[cur ^ 1][g * 4][0];
    #pragma unroll
    for (int tau = 0; tau < 4; ++tau) {
      f32x4 a = (tau == 0) ? acc0 : (tau == 1) ? acc1 : (tau == 2) ? acc2 : acc3;
      u32x2 xq = (tau == 0) ? xq0 : (tau == 1) ? xq1 : (tau == 2) ? xq2 : xq3;
      float t0 = tanh_fast(a.x + __uint_as_float((xq.x & 0xffffu) << 16));
      float t1 = tanh_fast(a.y + __uint_as_float(xq.x & 0xffff0000u));
      float t2 = tanh_fast(a.z + __uint_as_float((xq.y & 0xffffu) << 16));
      float t3 = tanh_fast(a.w + __uint_as_float(xq.y & 0xffff0000u));
      unsigned u01 = cvtpk(t0, t1), u23 = cvtpk(t2, t3);
      const int n = n_wave + tau * 16 + c;
      hw[n]        = (unsigned short)(u01 & 0xffffu);
      hw[n + 520]  = (unsigned short)(u01 >> 16);
      hw[n + 1040] = (unsigned short)(u23 & 0xffffu);
      hw[n + 1560] = (unsigned short)(u23 >> 16);
    }
    __syncthreads();
    cur ^= 1;
    xpp += (size_t)HID * BATCH;
  }

  // final h -> hT (f32), coalesced
  for (int i = tid; i < 16 * HID; i += 512) {
    const int row = i >> 9, n = i & (HID - 1);
    hT[(size_t)(wg * 16 + row) * HID + n] =
        __uint_as_float((unsigned)hbuf[cur][row][n] << 16);
  }
}

// ---------------------------------------------------------------------------
// K3: out[b][c] = hT[b] . W_fc[c] + b_fc[c]
// ---------------------------------------------------------------------------
__global__ __launch_bounds__(256) void k3_head(
    const float* __restrict__ hT, const float* __restrict__ Wfc,
    const float* __restrict__ bfc, float* __restrict__ out) {
  __shared__ float hrow[HID];
  const int b = blockIdx.x, tid = threadIdx.x;
  hrow[tid] = hT[(size_t)b * HID + tid];
  hrow[tid + 256] = hT[(size_t)b * HID + tid + 256];
  __syncthreads();
  for (int cc = tid; cc < NCLS; cc += 256) {
    const f32x4* W4 = (const f32x4*)(Wfc + (size_t)cc * HID);
    float s0 = 0, s1 = 0, s2 = 0, s3 = 0;
    #pragma unroll 4
    for (int j = 0; j < HID / 4; ++j) {
      f32x4 w = W4[j];
      f32x4 h4 = *(const f32x4*)(hrow + j * 4);
      s0 += h4.x * w.x; s1 += h4.y * w.y; s2 += h4.z * w.z; s3 += h4.w * w.w;
    }
    out[(size_t)b * NCLS + cc] = bfc[cc] + s0 + s1 + s2 + s3;
  }
}

extern "C" void kernel_launch(void* const* d_in, const int* in_sizes, int n_in,
                              void* d_out, int out_size, void* d_ws, size_t ws_size,
                              hipStream_t stream) {
  (void)in_sizes; (void)n_in; (void)out_size; (void)ws_size;
  const int*   x   = (const int*)d_in[0];
  const float* emb = (const float*)d_in[1];
  const float* Wih = (const float*)d_in[2];
  const float* Whh = (const float*)d_in[3];
  const float* bih = (const float*)d_in[4];
  const float* bhh = (const float*)d_in[5];
  const float* Wfc = (const float*)d_in[6];
  const float* bfc = (const float*)d_in[7];
  float* out = (float*)d_out;

  // ws: xp bf16 [T][HID][B] 33,554,432 B | hT f32 131,072 B | wpack 524,288 B
  unsigned short* xp = (unsigned short*)d_ws;
  float* hT = (float*)((char*)d_ws + (size_t)T_STEPS * HID * BATCH * 2);
  unsigned short* wpack = (unsigned short*)((char*)d_ws + (size_t)T_STEPS * HID * BATCH * 2 + (size_t)BATCH * HID * 4);

  k0_pack<<<128, 256, 0, stream>>>(Whh, wpack);
  k1_embed_proj<<<512, 256, 0, stream>>>(x, emb, Wih, bih, bhh, xp);
  k2_rnn<<<4, 512, 0, stream>>>(wpack, xp, hT);
  k3_head<<<64, 256, 0, stream>>>(hT, Wfc, bfc, out);
}

// Round 5
// 969.170 us; speedup vs baseline: 2.5282x; 2.5282x over previous
//
#include <hip/hip_runtime.h>
#include <hip/hip_bf16.h>

#define T_STEPS 512
#define HID 512
#define EMB_D 300
#define BATCH 64
#define NCLS 1000

typedef __attribute__((ext_vector_type(4))) float f32x4;
typedef __attribute__((ext_vector_type(8))) short bf16x8;
typedef __attribute__((ext_vector_type(4))) unsigned int u32x4;
typedef __attribute__((ext_vector_type(2))) unsigned int u32x2;

union FragU { u32x4 u; bf16x8 b; };

__device__ __forceinline__ unsigned cvtpk(float lo, float hi) {
  unsigned r;
  asm("v_cvt_pk_bf16_f32 %0, %1, %2" : "=v"(r) : "v"(lo), "v"(hi));
  return r;
}

__device__ __forceinline__ bf16x8 pack8(f32x4 lo, f32x4 hi) {
  FragU u;
  u.u = (u32x4){cvtpk(lo.x, lo.y), cvtpk(lo.z, lo.w), cvtpk(hi.x, hi.y), cvtpk(hi.z, hi.w)};
  return u.b;
}

__device__ __forceinline__ float tanh_fast(float x) {
  x = fminf(15.0f, fmaxf(-15.0f, x));
  float e = __builtin_amdgcn_exp2f(x * 2.8853900817779268f);
  return (e - 1.0f) * __builtin_amdgcn_rcpf(e + 1.0f);
}

__device__ __forceinline__ float bf16lo(unsigned u) { return __uint_as_float(u << 16); }
__device__ __forceinline__ float bf16hi(unsigned u) { return __uint_as_float(u & 0xffff0000u); }

#define MFMA16(A, B, C) __builtin_amdgcn_mfma_f32_16x16x32_bf16(A, B, C, 0, 0, 0)

// ---------------------------------------------------------------------------
// K0: pack W_hh (f32) -> bf16 MFMA fragments.
// wpack[wv 8][tile 4][kk 16][lane 64][e 8] = Whh[wv*64+tile*16+(lane&15)][kk*32+(lane>>4)*8+e]
// Used as the A operand (A row = lane&15 = n, k = (lane>>4)*8+e).
// ---------------------------------------------------------------------------
__global__ __launch_bounds__(256) void k0_pack(const float* __restrict__ Whh,
                                               unsigned short* __restrict__ wpack) {
  const int idx = blockIdx.x * 256 + threadIdx.x;  // 0..32767 lane-frags
  const int lane = idx & 63;
  const int kk = (idx >> 6) & 15;
  const int tw = (idx >> 10) & 3;
  const int wv = idx >> 12;
  const int c = lane & 15, g = lane >> 4;
  const int i = wv * 64 + tw * 16 + c;
  const int j = kk * 32 + g * 8;
  f32x4 lo = *(const f32x4*)(Whh + (size_t)i * HID + j);
  f32x4 hi = *(const f32x4*)(Whh + (size_t)i * HID + j + 4);
  *(bf16x8*)(wpack + (size_t)idx * 8) = pack8(lo, hi);
}

// ---------------------------------------------------------------------------
// K1 v3 (swapped operands): xp = emb[x] . W_ih^T + b_ih + b_hh, stored TILE-PACKED:
// xp[t][a 4][tile 32][lane 64][4 shorts]; entry = 4 consecutive n (g*4..+3) for
// batch row a*16+c. One block per t: stage 64 emb rows to LDS bf16 once.
// ---------------------------------------------------------------------------
__global__ __launch_bounds__(256) void k1_embed_proj(
    const int* __restrict__ x, const float* __restrict__ emb,
    const float* __restrict__ Wih, const float* __restrict__ bih,
    const float* __restrict__ bhh, unsigned short* __restrict__ xp) {
  __shared__ unsigned short xe[64][328];   // 656B row stride: 16B aligned
  __shared__ int xi[64];
  const int tid = threadIdx.x;
  const int t = blockIdx.x;
  if (tid < 64) xi[tid] = x[tid * T_STEPS + t];
  __syncthreads();
  {
    const int r = tid >> 2, q = tid & 3;
    const float* src = emb + (size_t)xi[r] * EMB_D;
    for (int jp = q; jp < 150; jp += 4) {
      const int j = jp * 2;
      *(unsigned*)&xe[r][j] = cvtpk(src[j], src[j + 1]);
    }
    if (q == 3) {
      #pragma unroll
      for (int j = 300; j < 328; j += 2) *(unsigned*)&xe[r][j] = 0;  // zero K-pad
    }
  }
  __syncthreads();

  const int wv = tid >> 6, lane = tid & 63;
  const int c = lane & 15, g = lane >> 4;
  const f32x4 z4 = {0, 0, 0, 0};

  bf16x8 af[4][10];                         // B operand: col=c=batch a*16+c, k=g*8+e
  #pragma unroll
  for (int a = 0; a < 4; ++a) {
    #pragma unroll
    for (int kk = 0; kk < 10; ++kk)
      af[a][kk] = *(const bf16x8*)&xe[a * 16 + c][kk * 32 + g * 8];
  }

  #pragma unroll 1
  for (int nt8 = 0; nt8 < 8; ++nt8) {
    const int nt = wv * 8 + nt8;
    const int n = nt * 16 + c;              // A row (n-dim)
    f32x4 a0 = z4, a1 = z4, a2 = z4, a3 = z4;
    #pragma unroll
    for (int kk = 0; kk < 10; ++kk) {
      const int k0 = kk * 32 + g * 8;
      f32x4 blo = (k0 < EMB_D) ? *(const f32x4*)(Wih + (size_t)n * EMB_D + k0) : z4;
      f32x4 bhi = (k0 + 4 < EMB_D) ? *(const f32x4*)(Wih + (size_t)n * EMB_D + k0 + 4) : z4;
      bf16x8 wfrag = pack8(blo, bhi);       // A operand: row=c -> n, k=g*8+e
      a0 = MFMA16(wfrag, af[0][kk], a0);
      a1 = MFMA16(wfrag, af[1][kk], a1);
      a2 = MFMA16(wfrag, af[2][kk], a2);
      a3 = MFMA16(wfrag, af[3][kk], a3);
    }
    // D: col=c=batch, row=g*4+r = n within tile -> 4 consecutive n per lane
    const int n0 = nt * 16 + g * 4;
    f32x4 bias4 = *(const f32x4*)(bih + n0) + *(const f32x4*)(bhh + n0);
    #pragma unroll
    for (int a = 0; a < 4; ++a) {
      f32x4 o = ((a == 0) ? a0 : (a == 1) ? a1 : (a == 2) ? a2 : a3) + bias4;
      u32x2 pk = {cvtpk(o.x, o.y), cvtpk(o.z, o.w)};
      *(u32x2*)(xp + ((((size_t)t * 4 + a) * 32 + nt) * 64 + lane) * 4) = pk;
    }
  }
}

// ---------------------------------------------------------------------------
// K2 v3: persistent RNN, 4 WGs x 512 thr (8 waves). Swapped operands:
// acc_tau lane -> (batch=c, n = wv*64+tau*16+g*4..+3). Weights: tiles 0,1,2 +
// tile3/kk0 register-resident, tile3/kk1..15 in LDS. Explicit 2-deep prefetch
// of h-frag and LDS weight frag. h double-buffered in LDS; b64 writes
// (conflict-free); xq: one coalesced 512B load per (tau); next-step xq issued
// before the barrier.
// ---------------------------------------------------------------------------
__global__ __launch_bounds__(512) void k2_rnn(
    const unsigned short* __restrict__ wpack,
    const unsigned short* __restrict__ xp, float* __restrict__ hT) {
  __shared__ unsigned short hbuf[2][16][520];     // 33,280 B
  __shared__ unsigned short wlds[8][15][512];     // 122,880 B

  const int tid = threadIdx.x;
  const int wv = tid >> 6, lane = tid & 63;
  const int c = lane & 15, g = lane >> 4;
  const int wg = blockIdx.x;                      // batch rows wg*16..+15
  const int n_wave = wv * 64;

  // ---- weights: A-operand fragments ----
  const unsigned short* wp = wpack + (size_t)wv * 64 * 512 + (size_t)lane * 8;
  bf16x8 wr0[16], wr1[16], wr2[16], w30;
  #pragma unroll
  for (int kk = 0; kk < 16; ++kk) {
    wr0[kk] = *(const bf16x8*)(wp + (size_t)kk * 512);
    wr1[kk] = *(const bf16x8*)(wp + (size_t)(16 + kk) * 512);
    wr2[kk] = *(const bf16x8*)(wp + (size_t)(32 + kk) * 512);
  }
  w30 = *(const bf16x8*)(wp + (size_t)48 * 512);
  #pragma unroll
  for (int kk = 1; kk < 16; ++kk) {
    bf16x8 f = *(const bf16x8*)(wp + (size_t)(48 + kk) * 512);
    *(bf16x8*)&wlds[wv][kk - 1][lane * 8] = f;
  }

  for (int i = tid; i < 2 * 16 * 520; i += 512) ((unsigned short*)hbuf)[i] = 0;
  __syncthreads();

  // xq: tile-packed xp; per tau one contiguous 512B wave load
  const unsigned short* xpb =
      xp + (((size_t)0 * 4 + wg) * 32 + wv * 4) * 256 + (size_t)lane * 4;
  const size_t xstride = (size_t)4 * 32 * 256;    // shorts per t
  u32x2 xq0 = *(const u32x2*)(xpb);
  u32x2 xq1 = *(const u32x2*)(xpb + 256);
  u32x2 xq2 = *(const u32x2*)(xpb + 512);
  u32x2 xq3 = *(const u32x2*)(xpb + 768);

  int cur = 0;

  #pragma unroll 1
  for (int t = 0; t < T_STEPS; ++t) {
    f32x4 acc0 = {0,0,0,0}, acc1 = {0,0,0,0}, acc2 = {0,0,0,0}, acc3 = {0,0,0,0};
    const unsigned short* hb = &hbuf[cur][0][0];

    // 2-deep rolling prefetch: afc/w3c live, next loaded before use
    bf16x8 afc = *(const bf16x8*)(hb + c * 520 + g * 8);
    bf16x8 w3c = w30;
    #pragma unroll
    for (int kk = 0; kk < 16; ++kk) {
      bf16x8 afn = afc, w3n = w3c;
      if (kk < 15) {
        afn = *(const bf16x8*)(hb + c * 520 + (kk + 1) * 32 + g * 8);
        w3n = *(const bf16x8*)&wlds[wv][kk][lane * 8];
      }
      acc0 = MFMA16(wr0[kk], afc, acc0);
      acc1 = MFMA16(wr1[kk], afc, acc1);
      acc2 = MFMA16(wr2[kk], afc, acc2);
      acc3 = MFMA16(w3c, afc, acc3);
      afc = afn; w3c = w3n;
    }

    // tanh + b64 write: lane -> batch c, n = n_wave + tau*16 + g*4 .. +3
    unsigned short* hw = &hbuf[cur ^ 1][c][0];
    #pragma unroll
    for (int tau = 0; tau < 4; ++tau) {
      f32x4 a = (tau == 0) ? acc0 : (tau == 1) ? acc1 : (tau == 2) ? acc2 : acc3;
      u32x2 xq = (tau == 0) ? xq0 : (tau == 1) ? xq1 : (tau == 2) ? xq2 : xq3;
      float t0 = tanh_fast(a.x + bf16lo(xq.x));
      float t1 = tanh_fast(a.y + bf16hi(xq.x));
      float t2 = tanh_fast(a.z + bf16lo(xq.y));
      float t3 = tanh_fast(a.w + bf16hi(xq.y));
      u32x2 hv = {cvtpk(t0, t1), cvtpk(t2, t3)};
      *(u32x2*)(hw + n_wave + tau * 16 + g * 4) = hv;
    }

    // prefetch next step's xq BEFORE the barrier (latency hides under sync)
    if (t + 1 < T_STEPS) {
      const unsigned short* nx = xpb + (size_t)(t + 1) * xstride;
      xq0 = *(const u32x2*)(nx);
      xq1 = *(const u32x2*)(nx + 256);
      xq2 = *(const u32x2*)(nx + 512);
      xq3 = *(const u32x2*)(nx + 768);
    }
    __syncthreads();
    cur ^= 1;
  }

  // final h -> hT (f32), coalesced
  for (int i = tid; i < 16 * HID; i += 512) {
    const int row = i >> 9, n = i & (HID - 1);
    hT[(size_t)(wg * 16 + row) * HID + n] =
        __uint_as_float((unsigned)hbuf[cur][row][n] << 16);
  }
}

// ---------------------------------------------------------------------------
// K3: out[b][c] = hT[b] . W_fc[c] + b_fc[c]
// ---------------------------------------------------------------------------
__global__ __launch_bounds__(256) void k3_head(
    const float* __restrict__ hT, const float* __restrict__ Wfc,
    const float* __restrict__ bfc, float* __restrict__ out) {
  __shared__ float hrow[HID];
  const int b = blockIdx.x, tid = threadIdx.x;
  hrow[tid] = hT[(size_t)b * HID + tid];
  hrow[tid + 256] = hT[(size_t)b * HID + tid + 256];
  __syncthreads();
  for (int cc = tid; cc < NCLS; cc += 256) {
    const f32x4* W4 = (const f32x4*)(Wfc + (size_t)cc * HID);
    float s0 = 0, s1 = 0, s2 = 0, s3 = 0;
    #pragma unroll 4
    for (int j = 0; j < HID / 4; ++j) {
      f32x4 w = W4[j];
      f32x4 h4 = *(const f32x4*)(hrow + j * 4);
      s0 += h4.x * w.x; s1 += h4.y * w.y; s2 += h4.z * w.z; s3 += h4.w * w.w;
    }
    out[(size_t)b * NCLS + cc] = bfc[cc] + s0 + s1 + s2 + s3;
  }
}

extern "C" void kernel_launch(void* const* d_in, const int* in_sizes, int n_in,
                              void* d_out, int out_size, void* d_ws, size_t ws_size,
                              hipStream_t stream) {
  (void)in_sizes; (void)n_in; (void)out_size; (void)ws_size;
  const int*   x   = (const int*)d_in[0];
  const float* emb = (const float*)d_in[1];
  const float* Wih = (const float*)d_in[2];
  const float* Whh = (const float*)d_in[3];
  const float* bih = (const float*)d_in[4];
  const float* bhh = (const float*)d_in[5];
  const float* Wfc = (const float*)d_in[6];
  const float* bfc = (const float*)d_in[7];
  float* out = (float*)d_out;

  // ws: xp bf16 tile-packed 33,554,432 B | hT f32 131,072 B | wpack 524,288 B
  unsigned short* xp = (unsigned short*)d_ws;
  float* hT = (float*)((char*)d_ws + (size_t)T_STEPS * HID * BATCH * 2);
  unsigned short* wpack = (unsigned short*)((char*)d_ws + (size_t)T_STEPS * HID * BATCH * 2 + (size_t)BATCH * HID * 4);

  k0_pack<<<128, 256, 0, stream>>>(Whh, wpack);
  k1_embed_proj<<<512, 256, 0, stream>>>(x, emb, Wih, bih, bhh, xp);
  k2_rnn<<<4, 512, 0, stream>>>(wpack, xp, hT);
  k3_head<<<64, 256, 0, stream>>>(hT, Wfc, bfc, out);
}